// Round 3
// baseline (50964.487 us; speedup 1.0000x reference)
//
#include <hip/hip_runtime.h>
#include <cmath>

#define Bsz 64
#define Tsz 256
#define Hsz 1024
#define NWG 256
#define NTHR 256

// ---------------- device-global scratch -------------------------------------
__device__ float g_h[2][2][Bsz * Hsz];   // [layer][parity][b*H+k]
__device__ float g_pre[2][Bsz];          // [parity][b] gate pre-activation accum
__device__ float g_an[Tsz * Bsz];        // [t][b]: x[b,min(t+1,T-1)] . v1
__device__ float g_v1[Hsz];
__device__ float g_v2[Hsz];
__device__ float g_c;
__device__ unsigned g_cnt, g_gen;

// ---------------- grid barrier (256 WGs, generation-based) ------------------
__device__ __forceinline__ void gridbar(unsigned lgen) {
    __syncthreads();
    if (threadIdx.x == 0) {
        __threadfence();
        unsigned prev = atomicAdd(&g_cnt, 1u);
        if (prev == NWG - 1) {
            __hip_atomic_store(&g_cnt, 0u, __ATOMIC_RELAXED, __HIP_MEMORY_SCOPE_AGENT);
            __hip_atomic_store(&g_gen, lgen, __ATOMIC_RELEASE, __HIP_MEMORY_SCOPE_AGENT);
        } else {
            while (__hip_atomic_load(&g_gen, __ATOMIC_ACQUIRE, __HIP_MEMORY_SCOPE_AGENT) < lgen)
                __builtin_amdgcn_s_sleep(1);
        }
        __threadfence();
    }
    __syncthreads();
}

// ---------------- init ------------------------------------------------------
__global__ void k_init(const float* __restrict__ h0,
                       const float* __restrict__ gW1, const float* __restrict__ gb1,
                       const float* __restrict__ gW2, const float* __restrict__ gb2,
                       const float* __restrict__ gWF, const float* __restrict__ gbF) {
    int blk = blockIdx.x, tid = threadIdx.x;
    if (blk < 256) {
        int idx = blk * 256 + tid;
        float v = h0[idx & (Hsz - 1)];
        g_h[0][0][idx] = v;
        g_h[1][0][idx] = v;
    } else if (blk == 256) {
        __shared__ float red[256];
        float s = 0.f;
        for (int j = tid; j < Hsz; j += 256) s += gWF[j] * (gb1[j] + gb2[j]);
        red[tid] = s;
        __syncthreads();
        for (int off = 128; off > 0; off >>= 1) {
            if (tid < off) red[tid] += red[tid + off];
            __syncthreads();
        }
        if (tid == 0) g_c = red[0] + gbF[0];
        if (tid < 128) ((float*)g_pre)[tid] = 0.f;
        if (tid == 128) g_cnt = 0u;
        if (tid == 129) g_gen = 0u;
    } else if (blk < 261) {
        int k = (blk - 257) * 256 + tid;
        float s = 0.f;
        for (int j = 0; j < Hsz; ++j) s += gWF[j] * gW1[(size_t)j * Hsz + k];
        g_v1[k] = s;
    } else {
        int k = (blk - 261) * 256 + tid;
        float s = 0.f;
        for (int j = 0; j < Hsz; ++j) s += gWF[j] * gW2[(size_t)j * Hsz + k];
        g_v2[k] = s;
    }
}

// ---------------- precompute an[t][b] = x[b, min(t+1,T-1)] . v1 -------------
__global__ void k_an(const float* __restrict__ x) {
    int blk = blockIdx.x, tid = threadIdx.x;
    int lane = tid & 63, wv = tid >> 6;
    for (int i = 0; i < 16; ++i) {
        int o = blk * 64 + wv * 16 + i;      // [0, 16384)
        int b = o >> 8, tt = o & 255;
        int ts = (tt + 1 < Tsz) ? tt + 1 : Tsz - 1;
        const float* xp = x + ((size_t)b * Tsz + ts) * Hsz;
        float s = 0.f;
        for (int k = lane; k < Hsz; k += 64) s += xp[k] * g_v1[k];
        for (int m = 32; m > 0; m >>= 1) s += __shfl_xor(s, m, 64);
        if (lane == 0) g_an[tt * 64 + b] = s;
    }
}

// ---------------- one GRU layer phase (SGPR-weight GEMV) --------------------
// lane <-> b (64 lanes = 64 batches); WG owns 4 jn columns; wave w owns
// K-quarter [w*256, w*256+256) and, in the epilogue, column jn0+w.
// Rows r = jl*6 + m; m 0..2 = W_ih gates (r,z,n), m 3..5 = W_hh gates.
template <bool IS_L1>
__device__ __forceinline__ void do_phase(
    int t, int jn0,
    const float* __restrict__ a0, size_t a0s,            // gi-input rows
    const float* __restrict__ st, float* __restrict__ ho, // state in/out
    const float* __restrict__ Wi, const float* __restrict__ Wh,
    const float* __restrict__ bi, const float* __restrict__ bh,
    const float* __restrict__ h0, int lbR,
    float* __restrict__ outp,
    float* __restrict__ sbuf, const float* __restrict__ srst, float (*sg)[64]) {

    const int tid = threadIdx.x;
    const int lane = tid & 63;
    const int w = __builtin_amdgcn_readfirstlane(tid >> 6);  // wave-uniform SGPR
    const int kq0 = w * 256;
    float* swv = sbuf + w * (2 * 64 * 20);   // this wave's [2][64][20] window

    // weight row-base pointers: uniform (jn0 from blockIdx, m/jl unrolled)
    const float* wb[6];
#pragma unroll
    for (int g = 0; g < 3; ++g) {
        wb[g]     = Wi + (size_t)(g * Hsz + jn0) * Hsz;
        wb[3 + g] = Wh + (size_t)(g * Hsz + jn0) * Hsz;
    }

    float2 acc[24];
#pragma unroll
    for (int r = 0; r < 24; ++r) acc[r] = make_float2(0.f, 0.f);

    // staging assignment: i in 0..7 -> tensor=i>>2, b=(i&3)*16+(lane>>2), k4=lane&3
    float4 A[8], B[8];

    auto load_chunk = [&](int c, float4* dst) {
        const int kw = kq0 + c * 16;
        const int k = kw + (lane & 3) * 4;
#pragma unroll
        for (int i = 0; i < 8; ++i) {
            const int b = (i & 3) * 16 + (lane >> 2);
            float4 v;
            if (i < 4) {
                v = *(const float4*)(a0 + (size_t)b * a0s + k);
            } else {
                v = *(const float4*)(st + (size_t)b * Hsz + k);
                float4 hv = *(const float4*)(h0 + k);
                if (srst[b] != 0.f) v = hv;
            }
            dst[i] = v;
        }
    };
    auto write_chunk = [&](const float4* src) {
#pragma unroll
        for (int i = 0; i < 8; ++i) {
            const int tsr = i >> 2;
            const int b = (i & 3) * 16 + (lane >> 2);
            const int kk = (lane & 3) * 4;
            *(float4*)&swv[(tsr * 64 + b) * 20 + kk] = src[i];
        }
    };
    auto compute_chunk = [&](int c) {
        const int kw = kq0 + c * 16;
        for (int g4 = 0; g4 < 4; ++g4) {
            float4 ax = *(const float4*)&swv[lane * 20 + g4 * 4];
            float4 ah = *(const float4*)&swv[(64 + lane) * 20 + g4 * 4];
            const int k = kw + g4 * 4;
#pragma unroll
            for (int m = 0; m < 6; ++m) {
                const float* bp = wb[m] + k;
                const float ax0 = (m < 3) ? ax.x : ah.x;
                const float ax1 = (m < 3) ? ax.y : ah.y;
                const float ax2 = (m < 3) ? ax.z : ah.z;
                const float ax3 = (m < 3) ? ax.w : ah.w;
#pragma unroll
                for (int jl = 0; jl < 4; ++jl) {
                    const float* rp = bp + (size_t)jl * Hsz;   // uniform address
                    float2 w01 = *(const float2*)rp;
                    float2 w23 = *(const float2*)(rp + 2);
                    const int r = jl * 6 + m;
                    acc[r].x += ax0 * w01.x;
                    acc[r].y += ax1 * w01.y;
                    acc[r].x += ax2 * w23.x;
                    acc[r].y += ax3 * w23.y;
                }
            }
        }
    };

    // chunk loop: reg-double-buffered, per-wave windows -> no barriers inside
    load_chunk(0, A);
    for (int c = 0; c < 16; c += 2) {
        write_chunk(A);
        load_chunk(c + 1, B);
        compute_chunk(c);
        write_chunk(B);
        if (c + 2 < 16) load_chunk(c + 2, A);
        compute_chunk(c + 1);
    }

    // ---- cross-wave reduction (s_red aliases sbuf; barrier-protected) ------
    __syncthreads();   // everyone done reading their s_w windows
#pragma unroll
    for (int r = 0; r < 24; ++r)
        sbuf[(w * 24 + r) * 64 + lane] = acc[r].x + acc[r].y;

    // issue hprev load early (hidden behind the barrier + reduction)
    const int jn = jn0 + w;
    const float myrst = srst[lane];
    float hprev = st[(size_t)lane * Hsz + jn];
    __syncthreads();

    float s[6];
#pragma unroll
    for (int m = 0; m < 6; ++m) {
        float sm = 0.f;
#pragma unroll
        for (int v = 0; v < 4; ++v) sm += sbuf[(v * 24 + w * 6 + m) * 64 + lane];
        s[m] = sm;
    }
    if (myrst != 0.f) hprev = h0[jn];

    const float gir = s[0] + bi[jn], giz = s[1] + bi[Hsz + jn], gin = s[2] + bi[2 * Hsz + jn];
    const float ghr = s[3] + bh[jn], ghz = s[4] + bh[Hsz + jn], ghn = s[5] + bh[2 * Hsz + jn];
    const float r_ = 1.f / (1.f + __expf(-(gir + ghr)));
    const float z_ = 1.f / (1.f + __expf(-(giz + ghz)));
    const float n_ = tanhf(gin + r_ * ghn);
    const float hnew = (1.f - z_) * n_ + z_ * hprev;
    ho[(size_t)lane * Hsz + jn] = hnew;

    if (IS_L1) {
        outp[((size_t)lane * Tsz + t) * Hsz + jn] = (t < lbR) ? hnew : 0.f;
        sg[w][lane] = hnew * g_v2[jn];
        __syncthreads();
        if (w == 0) {
            float gp = sg[0][lane] + sg[1][lane] + sg[2][lane] + sg[3][lane];
            atomicAdd(&g_pre[t & 1][lane], gp);
        }
    }
}

// ---------------- main persistent cooperative kernel ------------------------
__global__ void __launch_bounds__(NTHR, 1)
k_main(const float* __restrict__ x, const float* __restrict__ h0,
       const int* __restrict__ lens,
       const float* __restrict__ W_ih, const float* __restrict__ W_hh,
       const float* __restrict__ b_ih, const float* __restrict__ b_hh,
       float* __restrict__ outp, float* __restrict__ gatep) {
    __shared__ __align__(16) float s_buf[4 * 2 * 64 * 20];  // 40 KB (aliased as s_red)
    __shared__ float s_rst[64];
    __shared__ float s_g[4][64];

    const int tid = threadIdx.x;
    const int wg = blockIdx.x;
    const int jn0 = wg * 4;
    const int lbR = lens[tid & 63];
    unsigned lgen = 0;

    const float* Wih1 = W_ih + (size_t)3 * Hsz * Hsz;
    const float* Whh1 = W_hh + (size_t)3 * Hsz * Hsz;
    const float* bi1 = b_ih + 3 * Hsz;
    const float* bh1 = b_hh + 3 * Hsz;

    for (int t = 0; t < Tsz; ++t) {
        const int p0 = t & 1, p1 = p0 ^ 1;

        // ---- prologue: reset flags from last step's gate; emit gate_z ------
        if (tid < 64) {
            float rstf = 0.f;
            if (t > 0) {
                const int tp = t - 1;
                const float pre = g_c + g_an[tp * 64 + tid] + g_pre[p1][tid];
                const bool il = (tp == lbR - 1);
                rstf = (il || pre > 0.f) ? 1.f : 0.f;
                if (wg == 0) {
                    const float gt = il ? 1.f : 1.f / (1.f + __expf(-pre));
                    gatep[(size_t)tid * Tsz + tp] = (tp < lbR) ? gt : 0.f;
                }
            }
            s_rst[tid] = rstf;
        }
        __syncthreads();

        // layer 0: gi from x_t
        do_phase<false>(t, jn0, x + (size_t)t * Hsz, (size_t)Tsz * Hsz,
                        g_h[0][p0], g_h[0][p1], W_ih, W_hh, b_ih, b_hh,
                        h0, lbR, outp, s_buf, s_rst, s_g);
        gridbar(++lgen);

        // zero next-step's gate accumulator (parity (t-1)&1, free this phase)
        if (wg == 0 && tid < 64) g_pre[p1][tid] = 0.f;

        // layer 1: gi from fresh h0new
        do_phase<true>(t, jn0, g_h[0][p1], (size_t)Hsz,
                       g_h[1][p0], g_h[1][p1], Wih1, Whh1, bi1, bh1,
                       h0, lbR, outp, s_buf, s_rst, s_g);
        gridbar(++lgen);
    }

    // tail: gate_z for tp = T-1
    if (wg == 0 && tid < 64) {
        const int tp = Tsz - 1;
        const float pre = g_c + g_an[tp * 64 + tid] + g_pre[tp & 1][tid];
        const bool il = (tp == lbR - 1);
        const float gt = il ? 1.f : 1.f / (1.f + __expf(-pre));
        gatep[(size_t)tid * Tsz + tp] = (tp < lbR) ? gt : 0.f;
    }
}

// ---------------- host launcher ---------------------------------------------
extern "C" void kernel_launch(void* const* d_in, const int* in_sizes, int n_in,
                              void* d_out, int out_size, void* d_ws, size_t ws_size,
                              hipStream_t stream) {
    const float* x = (const float*)d_in[0];
    const float* h0 = (const float*)d_in[1];
    const int* lens = (const int*)d_in[2];
    const float* W_ih = (const float*)d_in[3];
    const float* W_hh = (const float*)d_in[4];
    const float* b_ih = (const float*)d_in[5];
    const float* b_hh = (const float*)d_in[6];
    const float* gW1 = (const float*)d_in[7];
    const float* gb1 = (const float*)d_in[8];
    const float* gW2 = (const float*)d_in[9];
    const float* gb2 = (const float*)d_in[10];
    const float* gWF = (const float*)d_in[11];
    const float* gbF = (const float*)d_in[12];
    float* outp = (float*)d_out;
    float* gatep = outp + (size_t)Bsz * Tsz * Hsz;

    hipLaunchKernelGGL(k_init, dim3(265), dim3(256), 0, stream,
                       h0, gW1, gb1, gW2, gb2, gWF, gbF);
    hipLaunchKernelGGL(k_an, dim3(256), dim3(256), 0, stream, x);

    void* args[9] = { (void*)&x, (void*)&h0, (void*)&lens, (void*)&W_ih, (void*)&W_hh,
                      (void*)&b_ih, (void*)&b_hh, (void*)&outp, (void*)&gatep };
    hipError_t err = hipLaunchCooperativeKernel((const void*)k_main, dim3(NWG), dim3(NTHR),
                                                args, 0, stream);
    (void)err;
}

// Round 4
// 22599.515 us; speedup vs baseline: 2.2551x; 2.2551x over previous
//
#include <hip/hip_runtime.h>
#include <cmath>

#define Bsz 64
#define Tsz 256
#define Hsz 1024
#define NWG 256
#define NTHR 512
#define GRPWG 64   // workgroups per b-group (4 groups of 64)

// ---------------- device-global scratch -------------------------------------
__device__ float g_h[2][2][Bsz * Hsz];      // [layer][parity][b*H+k]
__device__ float g_pre[2][Bsz];             // [parity][b] gate partial accum
__device__ float g_an[Tsz * Bsz];           // [t][b]: x[b,min(t+1,T-1)] . v1
__device__ float g_v1[Hsz];
__device__ float g_v2[Hsz];
__device__ float g_c;
__device__ unsigned g_bar_cnt[4 * 32];      // padded per-group barrier state
__device__ unsigned g_bar_gen[4 * 32];
__device__ float g_gi0[(size_t)Tsz * Bsz * 3 * Hsz];  // 201 MB: x@Wih0^T + bih0

// ---------------- per-b-group barrier (64 WGs) ------------------------------
__device__ __forceinline__ void groupbar(int bg, unsigned lgen) {
    __syncthreads();
    if (threadIdx.x == 0) {
        __threadfence();
        unsigned* cnt = &g_bar_cnt[bg * 32];
        unsigned* gen = &g_bar_gen[bg * 32];
        unsigned prev = atomicAdd(cnt, 1u);
        if (prev == GRPWG - 1) {
            __hip_atomic_store(cnt, 0u, __ATOMIC_RELAXED, __HIP_MEMORY_SCOPE_AGENT);
            __hip_atomic_store(gen, lgen, __ATOMIC_RELEASE, __HIP_MEMORY_SCOPE_AGENT);
        } else {
            while (__hip_atomic_load(gen, __ATOMIC_ACQUIRE, __HIP_MEMORY_SCOPE_AGENT) < lgen)
                __builtin_amdgcn_s_sleep(1);
        }
        __threadfence();
    }
    __syncthreads();
}

// ---------------- init ------------------------------------------------------
__global__ void k_init(const float* __restrict__ h0,
                       const float* __restrict__ gW1, const float* __restrict__ gb1,
                       const float* __restrict__ gW2, const float* __restrict__ gb2,
                       const float* __restrict__ gWF, const float* __restrict__ gbF) {
    int blk = blockIdx.x, tid = threadIdx.x;
    if (blk < 256) {
        int idx = blk * 256 + tid;
        float v = h0[idx & (Hsz - 1)];
        g_h[0][0][idx] = v;
        g_h[1][0][idx] = v;
    } else if (blk == 256) {
        __shared__ float red[256];
        float s = 0.f;
        for (int j = tid; j < Hsz; j += 256) s += gWF[j] * (gb1[j] + gb2[j]);
        red[tid] = s;
        __syncthreads();
        for (int off = 128; off > 0; off >>= 1) {
            if (tid < off) red[tid] += red[tid + off];
            __syncthreads();
        }
        if (tid == 0) g_c = red[0] + gbF[0];
        if (tid < 128) ((float*)g_pre)[tid] = 0.f;
        if (tid >= 128 && tid < 256) {
            g_bar_cnt[tid - 128] = 0u;
            g_bar_gen[tid - 128] = 0u;
        }
    } else if (blk < 261) {
        int k = (blk - 257) * 256 + tid;
        float s = 0.f;
        for (int j = 0; j < Hsz; ++j) s += gWF[j] * gW1[(size_t)j * Hsz + k];
        g_v1[k] = s;
    } else {
        int k = (blk - 261) * 256 + tid;
        float s = 0.f;
        for (int j = 0; j < Hsz; ++j) s += gWF[j] * gW2[(size_t)j * Hsz + k];
        g_v2[k] = s;
    }
}

// ---------------- precompute an[t][b] = x[b, min(t+1,T-1)] . v1 -------------
__global__ void k_an(const float* __restrict__ x) {
    int blk = blockIdx.x, tid = threadIdx.x;
    int lane = tid & 63, wv = tid >> 6;
    for (int i = 0; i < 16; ++i) {
        int o = blk * 64 + wv * 16 + i;      // [0, 16384)
        int b = o >> 8, tt = o & 255;
        int ts = (tt + 1 < Tsz) ? tt + 1 : Tsz - 1;
        const float* xp = x + ((size_t)b * Tsz + ts) * Hsz;
        float s = 0.f;
        for (int k = lane; k < Hsz; k += 64) s += xp[k] * g_v1[k];
        for (int m = 32; m > 0; m >>= 1) s += __shfl_xor(s, m, 64);
        if (lane == 0) g_an[tt * 64 + b] = s;
    }
}

// ---------------- gi0 GEMM: g_gi0[t*64+b][n] = x[b,t,:].Wih0[n,:] + bih0[n] -
__global__ __launch_bounds__(256) void k_gemm(const float* __restrict__ x,
                                              const float* __restrict__ Wih,
                                              const float* __restrict__ bih) {
    __shared__ float As[16][132];
    __shared__ float Bs[16][132];
    const int tid = threadIdx.x;
    const int n0 = blockIdx.x * 128;   // 24 tiles
    const int m0 = blockIdx.y * 128;   // 128 tiles (C-row space r = t*64+b)
    const int tx = tid & 15, ty = tid >> 4;
    float acc[8][8] = {};

    for (int k0 = 0; k0 < Hsz; k0 += 16) {
#pragma unroll
        for (int i = 0; i < 2; ++i) {
            int task = tid * 2 + i;          // 0..511
            int rl = task >> 2;              // 0..127
            int kq = task & 3;
            int r = m0 + rl;
            int bb = r & 63, tt = r >> 6;
            float4 v = *(const float4*)(x + ((size_t)bb * Tsz + tt) * Hsz + k0 + kq * 4);
            As[kq * 4 + 0][rl] = v.x; As[kq * 4 + 1][rl] = v.y;
            As[kq * 4 + 2][rl] = v.z; As[kq * 4 + 3][rl] = v.w;
            float4 w = *(const float4*)(Wih + (size_t)(n0 + rl) * Hsz + k0 + kq * 4);
            Bs[kq * 4 + 0][rl] = w.x; Bs[kq * 4 + 1][rl] = w.y;
            Bs[kq * 4 + 2][rl] = w.z; Bs[kq * 4 + 3][rl] = w.w;
        }
        __syncthreads();
#pragma unroll
        for (int k = 0; k < 16; ++k) {
            float a[8], b[8];
            *(float4*)&a[0] = *(float4*)&As[k][ty * 8];
            *(float4*)&a[4] = *(float4*)&As[k][ty * 8 + 4];
            *(float4*)&b[0] = *(float4*)&Bs[k][tx * 8];
            *(float4*)&b[4] = *(float4*)&Bs[k][tx * 8 + 4];
#pragma unroll
            for (int i2 = 0; i2 < 8; ++i2)
#pragma unroll
                for (int j2 = 0; j2 < 8; ++j2) acc[i2][j2] += a[i2] * b[j2];
        }
        __syncthreads();
    }
#pragma unroll
    for (int i2 = 0; i2 < 8; ++i2) {
        int r = m0 + ty * 8 + i2;
        float* cp = g_gi0 + (size_t)r * (3 * Hsz) + n0 + tx * 8;
#pragma unroll
        for (int j2 = 0; j2 < 8; j2 += 4) {
            float4 v;
            v.x = acc[i2][j2 + 0] + bih[n0 + tx * 8 + j2 + 0];
            v.y = acc[i2][j2 + 1] + bih[n0 + tx * 8 + j2 + 1];
            v.z = acc[i2][j2 + 2] + bih[n0 + tx * 8 + j2 + 2];
            v.w = acc[i2][j2 + 3] + bih[n0 + tx * 8 + j2 + 3];
            *(float4*)(cp + j2) = v;
        }
    }
}

__device__ __forceinline__ float dot4(float4 a, float4 b) {
    return a.x * b.x + a.y * b.y + a.z * b.z + a.w * b.w;
}

// ---------------- one GRU layer phase ---------------------------------------
// 512 threads: 8 waves, wave w owns K-window [w*128, w*128+128).
// lane = (bi2: 8 b-pairs) x (ji2: 8 jn-pairs); WG tile 16b x 16jn.
// acc m-index: L1: 0=r(i+h merged),1=z(merged),2=i_n,3=h_n. L0: 0=h_r,1=h_z,2=h_n.
template <bool IS_L1>
__device__ __forceinline__ void do_phase(
    int t, int b0, int jn0,
    const float* __restrict__ a0,                         // L1 only: gi input rows
    const float* __restrict__ st, float* __restrict__ ho, // state in/out
    const float* __restrict__ Wi, const float* __restrict__ Wh,
    const float* __restrict__ bi, const float* __restrict__ bh,
    const float* __restrict__ h0, const int* __restrict__ lens,
    float* __restrict__ outp,
    float (*s_act)[2][16][36], float (*s_red)[4][16][16],
    const float* __restrict__ s_rst, float (*s_gs)[16]) {

    const int tid = threadIdx.x;
    const int wv = tid >> 6, lane = tid & 63;
    const int bi2 = (lane & 7) * 2, ji2 = (lane >> 3) * 2;
    const int kq0 = wv * 128;

    const float* wph[6];
    const float* wpi[6];
#pragma unroll
    for (int g = 0; g < 3; ++g)
#pragma unroll
        for (int dj = 0; dj < 2; ++dj) {
            int row = g * Hsz + jn0 + ji2 + dj;
            wph[g * 2 + dj] = Wh + (size_t)row * Hsz;
            if (IS_L1) wpi[g * 2 + dj] = Wi + (size_t)row * Hsz;
        }

    constexpr int NR = IS_L1 ? 4 : 2;   // staged float4 per lane per chunk
    constexpr int NM = IS_L1 ? 4 : 3;
    float acc[NM][2][2] = {};
    float4 A[NR], Bv[NR];

    auto load_chunk = [&](int c, float4* dst) {
        const int kb = kq0 + c * 32;
#pragma unroll
        for (int i = 0; i < NR; ++i) {
            int o = i * 64 + lane;
            int ts = o >> 7;                 // 0 always for L0
            int bb = (o >> 3) & 15, k4 = o & 7;
            int k = kb + k4 * 4;
            float4 v;
            if (IS_L1 && ts == 0) {
                v = *(const float4*)(a0 + (size_t)(b0 + bb) * Hsz + k);
            } else {
                v = *(const float4*)(st + (size_t)(b0 + bb) * Hsz + k);
                float4 hv = *(const float4*)(h0 + k);
                if (s_rst[bb] != 0.f) v = hv;
            }
            dst[i] = v;
        }
    };
    auto write_chunk = [&](const float4* src) {
#pragma unroll
        for (int i = 0; i < NR; ++i) {
            int o = i * 64 + lane;
            int ts = IS_L1 ? (o >> 7) : 0;
            int bb = (o >> 3) & 15, k4 = o & 7;
            *(float4*)&s_act[wv][ts][bb][k4 * 4] = src[i];
        }
    };
    auto compute_chunk = [&](int c) {
        const int kb = kq0 + c * 32;
#pragma unroll 2
        for (int kk = 0; kk < 32; kk += 4) {
            const int k = kb + kk;
            const int hs = IS_L1 ? 1 : 0;
            float4 hA = *(const float4*)&s_act[wv][hs][bi2][kk];
            float4 hB = *(const float4*)&s_act[wv][hs][bi2 + 1][kk];
            float4 xA, xB;
            if (IS_L1) {
                xA = *(const float4*)&s_act[wv][0][bi2][kk];
                xB = *(const float4*)&s_act[wv][0][bi2 + 1][kk];
            }
#pragma unroll
            for (int dj = 0; dj < 2; ++dj) {
                float4 whr = *(const float4*)(wph[0 * 2 + dj] + k);
                float4 whz = *(const float4*)(wph[1 * 2 + dj] + k);
                float4 whn = *(const float4*)(wph[2 * 2 + dj] + k);
                if (IS_L1) {
                    float4 wir = *(const float4*)(wpi[0 * 2 + dj] + k);
                    float4 wiz = *(const float4*)(wpi[1 * 2 + dj] + k);
                    float4 win = *(const float4*)(wpi[2 * 2 + dj] + k);
                    acc[0][0][dj] += dot4(xA, wir) + dot4(hA, whr);
                    acc[0][1][dj] += dot4(xB, wir) + dot4(hB, whr);
                    acc[1][0][dj] += dot4(xA, wiz) + dot4(hA, whz);
                    acc[1][1][dj] += dot4(xB, wiz) + dot4(hB, whz);
                    acc[2][0][dj] += dot4(xA, win);
                    acc[2][1][dj] += dot4(xB, win);
                    acc[3][0][dj] += dot4(hA, whn);
                    acc[3][1][dj] += dot4(hB, whn);
                } else {
                    acc[0][0][dj] += dot4(hA, whr);
                    acc[0][1][dj] += dot4(hB, whr);
                    acc[1][0][dj] += dot4(hA, whz);
                    acc[1][1][dj] += dot4(hB, whz);
                    acc[2][0][dj] += dot4(hA, whn);
                    acc[2][1][dj] += dot4(hB, whn);
                }
            }
        }
    };

    // chunk loop: reg double-buffered; per-wave LDS windows -> no barriers
    load_chunk(0, A);
#pragma unroll
    for (int c = 0; c < 4; c += 2) {
        write_chunk(A);
        load_chunk(c + 1, Bv);
        compute_chunk(c);
        write_chunk(Bv);
        if (c + 2 < 4) load_chunk(c + 2, A);
        compute_chunk(c + 1);
    }

    // ---- two-stage cross-wave reduce ---------------------------------------
    __syncthreads();
    if (wv >= 4) {
#pragma unroll
        for (int m = 0; m < NM; ++m)
#pragma unroll
            for (int db = 0; db < 2; ++db)
#pragma unroll
                for (int dj = 0; dj < 2; ++dj)
                    s_red[wv - 4][m][bi2 + db][ji2 + dj] = acc[m][db][dj];
    }
    __syncthreads();
    if (wv < 4) {
#pragma unroll
        for (int m = 0; m < NM; ++m)
#pragma unroll
            for (int db = 0; db < 2; ++db)
#pragma unroll
                for (int dj = 0; dj < 2; ++dj)
                    s_red[wv][m][bi2 + db][ji2 + dj] += acc[m][db][dj];
    }
    __syncthreads();

    // ---- epilogue ----------------------------------------------------------
    if (tid < 256) {
        const int ji = tid & 15, bI = tid >> 4;
        const int b = b0 + bI, jn = jn0 + ji;
        float hprev = st[(size_t)b * Hsz + jn];
        float g0r = 0.f, g0z = 0.f, g0n = 0.f;
        if (!IS_L1) {
            const float* gp = g_gi0 + (size_t)(t * 64 + b) * (3 * Hsz) + jn;
            g0r = gp[0]; g0z = gp[Hsz]; g0n = gp[2 * Hsz];
        }
        const int lb = lens[b];
        float s[NM];
#pragma unroll
        for (int m = 0; m < NM; ++m)
            s[m] = s_red[0][m][bI][ji] + s_red[1][m][bI][ji] +
                   s_red[2][m][bI][ji] + s_red[3][m][bI][ji];
        if (s_rst[bI] != 0.f) hprev = h0[jn];

        float pr, pz, pin, phn;
        if (IS_L1) {
            pr  = s[0] + bi[jn] + bh[jn];
            pz  = s[1] + bi[Hsz + jn] + bh[Hsz + jn];
            pin = s[2] + bi[2 * Hsz + jn];
            phn = s[3] + bh[2 * Hsz + jn];
        } else {
            pr  = g0r + s[0] + bh[jn];
            pz  = g0z + s[1] + bh[Hsz + jn];
            pin = g0n;
            phn = s[2] + bh[2 * Hsz + jn];
        }
        const float r_ = 1.f / (1.f + __expf(-pr));
        const float z_ = 1.f / (1.f + __expf(-pz));
        const float n_ = tanhf(pin + r_ * phn);
        const float hnew = (1.f - z_) * n_ + z_ * hprev;
        ho[(size_t)b * Hsz + jn] = hnew;
        if (IS_L1) {
            outp[((size_t)b * Tsz + t) * Hsz + jn] = (t < lb) ? hnew : 0.f;
            s_gs[bI][ji] = hnew * g_v2[jn];
        }
    }
    if (IS_L1) {
        __syncthreads();
        if (tid < 16) {
            float sm = 0.f;
#pragma unroll
            for (int j = 0; j < 16; ++j) sm += s_gs[tid][j];
            atomicAdd(&g_pre[t & 1][b0 + tid], sm);
        }
    }
}

// ---------------- main persistent cooperative kernel ------------------------
__global__ void __launch_bounds__(NTHR, 1)
k_main(const float* __restrict__ h0, const int* __restrict__ lens,
       const float* __restrict__ W_ih, const float* __restrict__ W_hh,
       const float* __restrict__ b_ih, const float* __restrict__ b_hh,
       float* __restrict__ outp, float* __restrict__ gatep) {
    __shared__ __align__(16) float s_act[8][2][16][36];  // 36.9 KB
    __shared__ float s_red[4][4][16][16];                // 16.4 KB
    __shared__ float s_rst[16];
    __shared__ float s_gs[16][16];

    const int tid = threadIdx.x;
    const int wg = blockIdx.x, bg = wg >> 6, jg = wg & 63;
    const int b0 = bg * 16, jn0 = jg * 16;
    unsigned lgen = 0;

    const float* Wih1 = W_ih + (size_t)3 * Hsz * Hsz;
    const float* Whh1 = W_hh + (size_t)3 * Hsz * Hsz;
    const float* bi1 = b_ih + 3 * Hsz;
    const float* bh1 = b_hh + 3 * Hsz;

    for (int t = 0; t < Tsz; ++t) {
        const int p0 = t & 1, p1 = p0 ^ 1;

        // prologue: reset flags from previous step's gate; emit gate_z
        if (tid < 16) {
            float rstf = 0.f;
            const int b = b0 + tid;
            const int lb = lens[b];
            if (t > 0) {
                const int tp = t - 1;
                const float pre = g_c + g_an[tp * 64 + b] + g_pre[p1][b];
                const bool il = (tp == lb - 1);
                rstf = (il || pre > 0.f) ? 1.f : 0.f;
                if (jg == 0) {
                    const float gt = il ? 1.f : 1.f / (1.f + __expf(-pre));
                    gatep[(size_t)b * Tsz + tp] = (tp < lb) ? gt : 0.f;
                }
            }
            s_rst[tid] = rstf;
        }
        __syncthreads();

        // layer 0: gi from precomputed g_gi0; only h-matmul here
        do_phase<false>(t, b0, jn0, nullptr,
                        g_h[0][p0], g_h[0][p1],
                        W_ih, W_hh, b_ih, b_hh, h0, lens,
                        outp, s_act, s_red, s_rst, s_gs);
        groupbar(bg, ++lgen);

        // zero next step's gate accumulator (parity p1, already consumed)
        if (jg == 0 && tid < 16) g_pre[p1][b0 + tid] = 0.f;

        // layer 1: gi from fresh h0new
        do_phase<true>(t, b0, jn0, g_h[0][p1],
                       g_h[1][p0], g_h[1][p1],
                       Wih1, Whh1, bi1, bh1, h0, lens,
                       outp, s_act, s_red, s_rst, s_gs);
        groupbar(bg, ++lgen);
    }

    // tail: gate_z for tp = T-1
    if (jg == 0 && tid < 16) {
        const int b = b0 + tid;
        const int lb = lens[b];
        const int tp = Tsz - 1;
        const float pre = g_c + g_an[tp * 64 + b] + g_pre[tp & 1][b];
        const bool il = (tp == lb - 1);
        const float gt = il ? 1.f : 1.f / (1.f + __expf(-pre));
        gatep[(size_t)b * Tsz + tp] = (tp < lb) ? gt : 0.f;
    }
}

// ---------------- host launcher ---------------------------------------------
extern "C" void kernel_launch(void* const* d_in, const int* in_sizes, int n_in,
                              void* d_out, int out_size, void* d_ws, size_t ws_size,
                              hipStream_t stream) {
    const float* x = (const float*)d_in[0];
    const float* h0 = (const float*)d_in[1];
    const int* lens = (const int*)d_in[2];
    const float* W_ih = (const float*)d_in[3];
    const float* W_hh = (const float*)d_in[4];
    const float* b_ih = (const float*)d_in[5];
    const float* b_hh = (const float*)d_in[6];
    const float* gW1 = (const float*)d_in[7];
    const float* gb1 = (const float*)d_in[8];
    const float* gW2 = (const float*)d_in[9];
    const float* gb2 = (const float*)d_in[10];
    const float* gWF = (const float*)d_in[11];
    const float* gbF = (const float*)d_in[12];
    float* outp = (float*)d_out;
    float* gatep = outp + (size_t)Bsz * Tsz * Hsz;

    hipLaunchKernelGGL(k_init, dim3(265), dim3(256), 0, stream,
                       h0, gW1, gb1, gW2, gb2, gWF, gbF);
    hipLaunchKernelGGL(k_an, dim3(256), dim3(256), 0, stream, x);
    hipLaunchKernelGGL(k_gemm, dim3(24, 128), dim3(256), 0, stream,
                       x, W_ih, b_ih);

    void* args[8] = { (void*)&h0, (void*)&lens, (void*)&W_ih, (void*)&W_hh,
                      (void*)&b_ih, (void*)&b_hh, (void*)&outp, (void*)&gatep };
    hipError_t err = hipLaunchCooperativeKernel((const void*)k_main, dim3(NWG), dim3(NTHR),
                                                args, 0, stream);
    (void)err;
}